// Round 4
// baseline (174.410 us; speedup 1.0000x reference)
//
#include <hip/hip_runtime.h>

#define BS 1024
#define D 128
#define NC 100000
#define NCP 100096           /* padded to 782*128 */
#define NTILES 782
#define S_SCALE 30.0f
#define MARGIN 0.35f
#define S2LOG2E 43.2808512f  /* 30 * log2(e): exp(30c-30) == exp2(fma(c,S2,-S2)) */

typedef __attribute__((ext_vector_type(8))) short bf16x8;
typedef __attribute__((ext_vector_type(4))) float f32x4;

__device__ __forceinline__ unsigned short f2bf(float f) {
    union { float f; unsigned u; } x; x.f = f;
    unsigned u = x.u;
    u += 0x7FFFu + ((u >> 16) & 1u);   // round-to-nearest-even
    return (unsigned short)(u >> 16);
}

// Fragment-sequential bf16 layout (operand-role-agnostic):
//   u32 index for (row r, lane l holding k=2l,2l+1):
//     (r>>4)*1024 + (l>>2)*64 + (r&15)*4 + (l&3)
// A 16-row x 32-k fragment is one CONTIGUOUS 1KB wave-load:
//     byte = (row_block)*4096 + ks*1024 + lane*16

// 4 rows per block (4 waves): l2-normalize input rows, emit f32 + frag bf16,
// count labels, and pos[row] = S * dot(fn, l2norm(weight[label])) in f32.
__global__ void prep_fn(const float* __restrict__ inp, const int* __restrict__ label,
                        const float* __restrict__ wt,
                        float* __restrict__ fn_f32, unsigned short* __restrict__ fn_fr,
                        float* __restrict__ counts, float* __restrict__ pos) {
    int row = blockIdx.x * 4 + (threadIdx.x >> 6);
    int lane = threadIdx.x & 63;
    float2 v = *(const float2*)(inp + row * D + lane * 2);
    float s = v.x * v.x + v.y * v.y;
    #pragma unroll
    for (int m = 1; m < 64; m <<= 1) s += __shfl_xor(s, m);
    float inv = 1.0f / fmaxf(sqrtf(s), 1e-12f);
    float a = v.x * inv, b = v.y * inv;
    *(float2*)(fn_f32 + row * D + lane * 2) = make_float2(a, b);
    unsigned pack = (unsigned)f2bf(a) | ((unsigned)f2bf(b) << 16);
    ((unsigned*)fn_fr)[(row >> 4) * 1024 + (lane >> 2) * 64 + ((row & 15) << 2) + (lane & 3)] = pack;

    int c = label[row];
    float2 wv = *(const float2*)(wt + c * D + lane * 2);
    float sw_ = wv.x * wv.x + wv.y * wv.y;
    float dt  = wv.x * a + wv.y * b;
    #pragma unroll
    for (int m = 1; m < 64; m <<= 1) { sw_ += __shfl_xor(sw_, m); dt += __shfl_xor(dt, m); }
    if (lane == 0) {
        float invw = 1.0f / fmaxf(sqrtf(sw_), 1e-12f);
        pos[row] = S_SCALE * dt * invw;
        atomicAdd(counts + c, 1.0f);
    }
}

// 4 waves/block, one weight row per wave: l2-normalize -> frag-layout bf16 global.
// Fused: write weight output (copy if class absent, 0 if present). Pad rows -> 0.
__global__ void prep_wn(const float* __restrict__ wt, const float* __restrict__ counts,
                        unsigned short* __restrict__ wn_fr, float* __restrict__ outw) {
    int wv = threadIdx.x >> 6, lane = threadIdx.x & 63;
    int row = blockIdx.x * 4 + wv;      // grid 25024 -> 100096 incl. pad
    unsigned* dst = (unsigned*)wn_fr + (row >> 4) * 1024 + (lane >> 2) * 64 +
                    ((row & 15) << 2) + (lane & 3);
    if (row < NC) {
        float2 v = *(const float2*)(wt + row * D + lane * 2);
        float s = v.x * v.x + v.y * v.y;
        #pragma unroll
        for (int m = 1; m < 64; m <<= 1) s += __shfl_xor(s, m);
        float inv = 1.0f / fmaxf(sqrtf(s), 1e-12f);
        *dst = (unsigned)f2bf(v.x * inv) | ((unsigned)f2bf(v.y * inv) << 16);
        float cnt = counts[row];
        float2 o = (cnt > 0.0f) ? make_float2(0.0f, 0.0f) : v;
        *(float2*)(outw + row * D + lane * 2) = o;
    } else {
        *dst = 0u;   // pad classes: zero vector -> logit 0 -> e^-30, negligible
    }
}

// Main fused GEMM + exp-accumulate. v5: same operand-swapped structure as v4
// (A = wn classes read once, B = fn batch streamed through regs, class axis in
// register indices so the exp-sum needs no cross-lane reduce), with two fixes:
//  (1) af[] pinned in VGPRs via opaque asm — R3's VGPR_Count=68 proved the
//      compiler was sinking the 16 "loop-invariant" A-fragment loads back into
//      the loop, exposing L2 latency on every chunk's MFMA phase. The volatile
//      asm pass-through makes rematerialization illegal. Expect VGPR ~150-170.
//  (2) grid split over batch (782 x 2, 8 chunks each): kills the 3.05-blocks/CU
//      dispatch tail (~25%) and doubles resident blocks for latency hiding.
__global__ __launch_bounds__(256, 3) void main_gemm(
    const unsigned short* __restrict__ fnfr, const unsigned short* __restrict__ wnfr,
    float* __restrict__ sumexp) {
    __shared__ float red[512];
    int tid = threadIdx.x;
    int lane = tid & 63, w = tid >> 6;
    int l15 = lane & 15;
    int cls_half = w >> 1;   // classes +0 / +64 within the 128-class tile
    int bat_half = w & 1;    // batch   +0 / +32 within the 64-batch chunk
    int ybase = blockIdx.y * 8;   // chunk range [ybase, ybase+8)

    red[tid] = 0.0f;
    red[tid + 256] = 0.0f;

    // A = wn tile fragments: 16 contiguous 1KB wave-loads, then pinned resident.
    bf16x8 af[4][4];   // [ks][mt]
    {
        const char* gA = (const char*)wnfr + (size_t)blockIdx.x * 32768 +
                         cls_half * 16384 + lane * 16;
        #pragma unroll
        for (int mt = 0; mt < 4; mt++)
            #pragma unroll
            for (int ks = 0; ks < 4; ks++)
                af[ks][mt] = *(const bf16x8*)(gA + mt * 4096 + ks * 1024);
    }
    // Opaque pass-through: af is now defined by a volatile asm the compiler
    // cannot duplicate or sink -> the loads above stay hoisted, af stays in VGPRs.
    #pragma unroll
    for (int ks = 0; ks < 4; ks++)
        #pragma unroll
        for (int mt = 0; mt < 4; mt++)
            asm volatile("" : "+v"(af[ks][mt]));

    __syncthreads();   // red[] zeroed before any ds atomic below

    const char* gB = (const char*)fnfr + (size_t)ybase * 16384 + bat_half * 8192 + lane * 16;

    bf16x8 b[2][4];    // [nt][ks] — single set, reloaded (WAR) after last MFMA use
    #pragma unroll
    for (int nt = 0; nt < 2; nt++)
        #pragma unroll
        for (int ks = 0; ks < 4; ks++)
            b[nt][ks] = *(const bf16x8*)(gB + nt * 4096 + ks * 1024);

    for (int c = 0; c < 8; c++) {
        f32x4 acc[4][2];
        #pragma unroll
        for (int mt = 0; mt < 4; mt++)
            #pragma unroll
            for (int nt = 0; nt < 2; nt++)
                acc[mt][nt] = (f32x4){0.0f, 0.0f, 0.0f, 0.0f};

        #pragma unroll
        for (int ks = 0; ks < 4; ks++)
            #pragma unroll
            for (int mt = 0; mt < 4; mt++)
                #pragma unroll
                for (int nt = 0; nt < 2; nt++)
                    acc[mt][nt] = __builtin_amdgcn_mfma_f32_16x16x32_bf16(
                        af[ks][mt], b[nt][ks], acc[mt][nt], 0, 0, 0);

        // Issue next chunk's fn loads NOW (b regs dead); L2-hit latency hides
        // under the exp epilogue below.
        if (c < 7) {
            const char* gBn = gB + (c + 1) * 16384;
            #pragma unroll
            for (int nt = 0; nt < 2; nt++)
                #pragma unroll
                for (int ks = 0; ks < 4; ks++)
                    b[nt][ks] = *(const bf16x8*)(gBn + nt * 4096 + ks * 1024);
        }

        // exp(30v-30) = exp2(fma(v, 30log2e, -30log2e)); class axis is (mt, r,
        // quad) -> per-lane sums over mt,r; then 2 shuffles fold the quads.
        float s0 = 0.0f, s1 = 0.0f;
        #pragma unroll
        for (int mt = 0; mt < 4; mt++)
            #pragma unroll
            for (int r = 0; r < 4; r++) {
                s0 += __builtin_amdgcn_exp2f(fmaf(acc[mt][0][r], S2LOG2E, -S2LOG2E));
                s1 += __builtin_amdgcn_exp2f(fmaf(acc[mt][1][r], S2LOG2E, -S2LOG2E));
            }
        s0 += __shfl_xor(s0, 16); s0 += __shfl_xor(s0, 32);
        s1 += __shfl_xor(s1, 16); s1 += __shfl_xor(s1, 32);
        if (lane < 16) {
            int base = c * 64 + bat_half * 32 + l15;
            atomicAdd(&red[base], s0);
            atomicAdd(&red[base + 16], s1);
        }
    }

    __syncthreads();
    atomicAdd(sumexp + blockIdx.y * 512 + tid, red[tid]);
    atomicAdd(sumexp + blockIdx.y * 512 + tid + 256, red[tid + 256]);
}

// loss = mean softplus(M + 30 + log(sum_all - exp(pos-30)) - pos)
__global__ void loss_k(const float* __restrict__ sumexp, const float* __restrict__ pos,
                       float* __restrict__ out) {
    __shared__ float red[256];
    int t = threadIdx.x;
    float acc = 0.0f;
    #pragma unroll
    for (int i = 0; i < 4; i++) {
        int r = t + i * 256;
        float p = pos[r];
        float sneg = fmaxf(sumexp[r] - __expf(p - 30.0f), 1e-38f);
        float lse = 30.0f + logf(sneg);
        float z = MARGIN + lse - p;
        acc += fmaxf(z, 0.0f) + log1pf(__expf(-fabsf(z)));
    }
    red[t] = acc;
    __syncthreads();
    for (int s = 128; s > 0; s >>= 1) {
        if (t < s) red[t] += red[t + s];
        __syncthreads();
    }
    if (t == 0) out[0] = red[0] * (1.0f / 1024.0f);
}

__global__ void addmean_k(const float* __restrict__ fn_f32, const int* __restrict__ label,
                          const float* __restrict__ counts, float* __restrict__ outw) {
    int b = blockIdx.x, t = threadIdx.x;  // 1024 x 128
    int c = label[b];
    float cnt = counts[c];
    atomicAdd(outw + c * D + t, fn_f32[b * D + t] / cnt);
}

extern "C" void kernel_launch(void* const* d_in, const int* in_sizes, int n_in,
                              void* d_out, int out_size, void* d_ws, size_t ws_size,
                              hipStream_t stream) {
    (void)in_sizes; (void)n_in; (void)out_size; (void)ws_size;
    const float* inp   = (const float*)d_in[0];
    const int*   label = (const int*)d_in[1];
    const float* wt    = (const float*)d_in[2];
    float* out = (float*)d_out;

    char* w = (char*)d_ws;
    float*          fn_f32 = (float*)(w);                     // 524288 B
    unsigned short* fn_fr  = (unsigned short*)(w + 524288);   // 262144 B
    unsigned short* wn_fr  = (unsigned short*)(w + 786432);   // 25624576 B
    float*          sumexp = (float*)(w + 26411008);          // 4096 B
    float*          counts = (float*)(w + 26415104);          // 400000 B
    float*          pos    = (float*)(w + 26815104);          // 4096 B

    // zero sumexp + counts (contiguous)
    hipMemsetAsync(w + 26411008, 0, 404096, stream);

    prep_fn<<<BS / 4, 256, 0, stream>>>(inp, label, wt, fn_f32, fn_fr, counts, pos);
    prep_wn<<<NCP / 4, 256, 0, stream>>>(wt, counts, wn_fr, out + 1);
    main_gemm<<<dim3(NTILES, 2), 256, 0, stream>>>(fn_fr, wn_fr, sumexp);
    addmean_k<<<BS, D, 0, stream>>>(fn_f32, label, counts, out + 1);
    loss_k<<<1, 256, 0, stream>>>(sumexp, pos, out);
}

// Round 5
// 160.332 us; speedup vs baseline: 1.0878x; 1.0878x over previous
//
#include <hip/hip_runtime.h>

#define BS 1024
#define D 128
#define NC 100000
#define NCP 100096           /* padded: 1564 * 64 */
#define NT64 1564            /* 64-class wn tiles */
#define PHASES 256           /* tile phases; grid = 256 x 2 halves = 2 blocks/CU */
#define S_SCALE 30.0f
#define MARGIN 0.35f
#define S2LOG2E 43.2808512f  /* 30 * log2(e): exp(30c-30) == exp2(fma(c,S2,-S2)) */

typedef __attribute__((ext_vector_type(8))) short bf16x8;
typedef __attribute__((ext_vector_type(4))) float f32x4;

__device__ __forceinline__ unsigned short f2bf(float f) {
    union { float f; unsigned u; } x; x.f = f;
    unsigned u = x.u;
    u += 0x7FFFu + ((u >> 16) & 1u);   // round-to-nearest-even
    return (unsigned short)(u >> 16);
}

// Async global->LDS, 16B per lane. Dest is wave-uniform base; HW adds lane*16.
__device__ __forceinline__ void gld_lds16(const void* g, void* l) {
    auto gp = (const __attribute__((address_space(1))) unsigned int*)(g);
    auto lp = (__attribute__((address_space(3))) unsigned int*)(l);
    __builtin_amdgcn_global_load_lds(gp, lp, 16, 0, 0);
}

// Fragment-sequential bf16 layout (operand-role-agnostic):
//   u32 index for (row r, lane l holding k=2l,2l+1):
//     (r>>4)*1024 + (l>>2)*64 + (r&15)*4 + (l&3)
// One 16-row x 32-k fragment = one CONTIGUOUS 1KB wave-load:
//     byte = (row_block)*4096 + ks*1024 + lane*16
// A 64-row tile = 16 KB contiguous -> linear global_load_lds staging.

// 4 rows per block (4 waves): l2-normalize input rows, emit f32 + frag bf16,
// count labels, and pos[row] = S * dot(fn, l2norm(weight[label])) in f32.
__global__ void prep_fn(const float* __restrict__ inp, const int* __restrict__ label,
                        const float* __restrict__ wt,
                        float* __restrict__ fn_f32, unsigned short* __restrict__ fn_fr,
                        float* __restrict__ counts, float* __restrict__ pos) {
    int row = blockIdx.x * 4 + (threadIdx.x >> 6);
    int lane = threadIdx.x & 63;
    float2 v = *(const float2*)(inp + row * D + lane * 2);
    float s = v.x * v.x + v.y * v.y;
    #pragma unroll
    for (int m = 1; m < 64; m <<= 1) s += __shfl_xor(s, m);
    float inv = 1.0f / fmaxf(sqrtf(s), 1e-12f);
    float a = v.x * inv, b = v.y * inv;
    *(float2*)(fn_f32 + row * D + lane * 2) = make_float2(a, b);
    unsigned pack = (unsigned)f2bf(a) | ((unsigned)f2bf(b) << 16);
    ((unsigned*)fn_fr)[(row >> 4) * 1024 + (lane >> 2) * 64 + ((row & 15) << 2) + (lane & 3)] = pack;

    int c = label[row];
    float2 wv = *(const float2*)(wt + c * D + lane * 2);
    float sw_ = wv.x * wv.x + wv.y * wv.y;
    float dt  = wv.x * a + wv.y * b;
    #pragma unroll
    for (int m = 1; m < 64; m <<= 1) { sw_ += __shfl_xor(sw_, m); dt += __shfl_xor(dt, m); }
    if (lane == 0) {
        float invw = 1.0f / fmaxf(sqrtf(sw_), 1e-12f);
        pos[row] = S_SCALE * dt * invw;
        atomicAdd(counts + c, 1.0f);
    }
}

// 4 waves/block, one weight row per wave: l2-normalize -> frag-layout bf16 global.
// Fused: write weight output (copy if class absent, 0 if present). Pad rows -> 0.
__global__ void prep_wn(const float* __restrict__ wt, const float* __restrict__ counts,
                        unsigned short* __restrict__ wn_fr, float* __restrict__ outw) {
    int wv = threadIdx.x >> 6, lane = threadIdx.x & 63;
    int row = blockIdx.x * 4 + wv;      // grid 25024 -> 100096 incl. pad
    unsigned* dst = (unsigned*)wn_fr + (row >> 4) * 1024 + (lane >> 2) * 64 +
                    ((row & 15) << 2) + (lane & 3);
    if (row < NC) {
        float2 v = *(const float2*)(wt + row * D + lane * 2);
        float s = v.x * v.x + v.y * v.y;
        #pragma unroll
        for (int m = 1; m < 64; m <<= 1) s += __shfl_xor(s, m);
        float inv = 1.0f / fmaxf(sqrtf(s), 1e-12f);
        *dst = (unsigned)f2bf(v.x * inv) | ((unsigned)f2bf(v.y * inv) << 16);
        float cnt = counts[row];
        float2 o = (cnt > 0.0f) ? make_float2(0.0f, 0.0f) : v;
        *(float2*)(outw + row * D + lane * 2) = o;
    } else {
        *dst = 0u;   // pad classes: zero vector -> logit 0 -> e^-30, negligible
    }
}

// Main fused GEMM + exp-accumulate. v6: traffic-minimal.
// Post-mortem R0-R4: every prior variant moved 200-400 MB through L2/L3 (wn or fn
// re-reads) and all landed at traffic / (4-8.5 TB/s) ~= 47-52 us -> cache-BW-bound.
// This version cuts traffic to ~25-50 MB wn (read ~once; phase-twin block on the
// same XCD L2-hits the second read) + 64 MB fn L2:
//   block = 1024 thr (16 waves), one batch-half (512 rows);
//   wave holds its 32 fn rows in 32 VGPRs (B-operand, read once);
//   wn streams as 64-class/16KB tiles through a 2x16KB LDS double buffer,
//   one global_load_lds per thread per tile, prefetch issued before compute,
//   ONE barrier per tile (vmcnt0 drain covered by ~1300cy MFMA+exp);
//   exp-sums live in 2 regs/lane across ALL tiles (batch axis = lanes),
//   folded over quads and flushed once at the end.
__global__ __launch_bounds__(1024, 4) void main_gemm(
    const unsigned short* __restrict__ fnfr, const unsigned short* __restrict__ wnfr,
    float* __restrict__ sumexp) {
    __shared__ __align__(16) short Ws[2][8192];   // 2 x 16 KB wn tiles
    int tid = threadIdx.x;
    int lane = tid & 63, w = tid >> 6;            // 16 waves
    int half = blockIdx.y;                        // batch half (512 rows)
    int rb0 = half * 32 + w * 2;                  // wave's fn row-block base

    // fn B-fragments in regs (32 VGPRs), loaded once, pinned.
    bf16x8 bf[2][4];  // [cg][ks]
    {
        const char* gB = (const char*)fnfr + (size_t)rb0 * 4096 + lane * 16;
        #pragma unroll
        for (int cg = 0; cg < 2; cg++)
            #pragma unroll
            for (int ks = 0; ks < 4; ks++)
                bf[cg][ks] = *(const bf16x8*)(gB + cg * 4096 + ks * 1024);
    }
    #pragma unroll
    for (int cg = 0; cg < 2; cg++)
        #pragma unroll
        for (int ks = 0; ks < 4; ks++)
            asm volatile("" : "+v"(bf[cg][ks]));

    float sums[2] = {0.0f, 0.0f};

    // prologue: stage tile t0 into buf 0 (each thread copies 16 B, 16 KB total)
    int t0 = blockIdx.x;
    {
        const char* g = (const char*)wnfr + (size_t)t0 * 16384 + w * 1024 + lane * 16;
        gld_lds16(g, (char*)Ws[0] + w * 1024);
    }
    __syncthreads();

    int cur = 0;
    for (int t = t0; t < NT64; t += PHASES) {
        // prefetch next tile into the other buffer (in flight across the compute)
        int nxt = t + PHASES;
        if (nxt < NT64) {
            const char* g = (const char*)wnfr + (size_t)nxt * 16384 + w * 1024 + lane * 16;
            gld_lds16(g, (char*)Ws[cur ^ 1] + w * 1024);
        }

        f32x4 acc[4][2];
        #pragma unroll
        for (int ag = 0; ag < 4; ag++)
            #pragma unroll
            for (int cg = 0; cg < 2; cg++)
                acc[ag][cg] = (f32x4){0.0f, 0.0f, 0.0f, 0.0f};

        const char* W = (const char*)Ws[cur];
        #pragma unroll
        for (int ks = 0; ks < 4; ks++) {
            bf16x8 a[4];
            #pragma unroll
            for (int ag = 0; ag < 4; ag++)
                a[ag] = *(const bf16x8*)(W + ag * 4096 + ks * 1024 + lane * 16);
            #pragma unroll
            for (int ag = 0; ag < 4; ag++)
                #pragma unroll
                for (int cg = 0; cg < 2; cg++)
                    acc[ag][cg] = __builtin_amdgcn_mfma_f32_16x16x32_bf16(
                        a[ag], bf[cg][ks], acc[ag][cg], 0, 0, 0);
        }

        // exp(30v-30) = exp2(fma(v, 30log2e, -30log2e)); class axis lives in
        // (ag, r, quad) -> pure per-lane sums, no cross-lane work per tile.
        #pragma unroll
        for (int ag = 0; ag < 4; ag++)
            #pragma unroll
            for (int cg = 0; cg < 2; cg++)
                #pragma unroll
                for (int r = 0; r < 4; r++)
                    sums[cg] += __builtin_amdgcn_exp2f(
                        fmaf(acc[ag][cg][r], S2LOG2E, -S2LOG2E));

        __syncthreads();   // drains prefetch (vmcnt 0) + all Ws[cur] reads
        cur ^= 1;
    }

    // fold the quad axis (rows 4q+r live in quads) and flush once.
    #pragma unroll
    for (int cg = 0; cg < 2; cg++) {
        float s = sums[cg];
        s += __shfl_xor(s, 16);
        s += __shfl_xor(s, 32);
        if (lane < 16)
            atomicAdd(sumexp + half * 512 + w * 32 + cg * 16 + lane, s);
    }
}

// loss = mean softplus(M + 30 + log(sum_all - exp(pos-30)) - pos)
__global__ void loss_k(const float* __restrict__ sumexp, const float* __restrict__ pos,
                       float* __restrict__ out) {
    __shared__ float red[256];
    int t = threadIdx.x;
    float acc = 0.0f;
    #pragma unroll
    for (int i = 0; i < 4; i++) {
        int r = t + i * 256;
        float p = pos[r];
        float sneg = fmaxf(sumexp[r] - __expf(p - 30.0f), 1e-38f);
        float lse = 30.0f + logf(sneg);
        float z = MARGIN + lse - p;
        acc += fmaxf(z, 0.0f) + log1pf(__expf(-fabsf(z)));
    }
    red[t] = acc;
    __syncthreads();
    for (int s = 128; s > 0; s >>= 1) {
        if (t < s) red[t] += red[t + s];
        __syncthreads();
    }
    if (t == 0) out[0] = red[0] * (1.0f / 1024.0f);
}

__global__ void addmean_k(const float* __restrict__ fn_f32, const int* __restrict__ label,
                          const float* __restrict__ counts, float* __restrict__ outw) {
    int b = blockIdx.x, t = threadIdx.x;  // 1024 x 128
    int c = label[b];
    float cnt = counts[c];
    atomicAdd(outw + c * D + t, fn_f32[b * D + t] / cnt);
}

extern "C" void kernel_launch(void* const* d_in, const int* in_sizes, int n_in,
                              void* d_out, int out_size, void* d_ws, size_t ws_size,
                              hipStream_t stream) {
    (void)in_sizes; (void)n_in; (void)out_size; (void)ws_size;
    const float* inp   = (const float*)d_in[0];
    const int*   label = (const int*)d_in[1];
    const float* wt    = (const float*)d_in[2];
    float* out = (float*)d_out;

    char* w = (char*)d_ws;
    float*          fn_f32 = (float*)(w);                     // 524288 B
    unsigned short* fn_fr  = (unsigned short*)(w + 524288);   // 262144 B
    unsigned short* wn_fr  = (unsigned short*)(w + 786432);   // 25624576 B (1564*16384)
    float*          sumexp = (float*)(w + 26411008);          // 4096 B
    float*          counts = (float*)(w + 26415104);          // 400000 B
    float*          pos    = (float*)(w + 26815104);          // 4096 B

    // zero sumexp + counts (contiguous)
    hipMemsetAsync(w + 26411008, 0, 404096, stream);

    prep_fn<<<BS / 4, 256, 0, stream>>>(inp, label, wt, fn_f32, fn_fr, counts, pos);
    prep_wn<<<NCP / 4, 256, 0, stream>>>(wt, counts, wn_fr, out + 1);
    main_gemm<<<dim3(PHASES, 2), 1024, 0, stream>>>(fn_fr, wn_fr, sumexp);
    addmean_k<<<BS, D, 0, stream>>>(fn_f32, label, counts, out + 1);
    loss_k<<<1, 256, 0, stream>>>(sumexp, pos, out);
}

// Round 6
// 139.304 us; speedup vs baseline: 1.2520x; 1.1509x over previous
//
#include <hip/hip_runtime.h>

#define BS 1024
#define D 128
#define NC 100000
#define NCP 100096           /* padded: 1564 * 64 */
#define NT64 1564            /* 64-class tiles */
#define PHASES 256           /* tile phases; grid = 256 x 2 halves = 512 blocks */
#define S_SCALE 30.0f
#define MARGIN 0.35f
#define S2LOG2E 43.2808512f  /* 30 * log2(e): exp(30c-30) == exp2(fma(c,S2,-S2)) */

typedef __attribute__((ext_vector_type(8))) short bf16x8;
typedef __attribute__((ext_vector_type(4))) float f32x4;

__device__ __forceinline__ unsigned short f2bf(float f) {
    union { float f; unsigned u; } x; x.f = f;
    unsigned u = x.u;
    u += 0x7FFFu + ((u >> 16) & 1u);   // round-to-nearest-even
    return (unsigned short)(u >> 16);
}

// Fragment-sequential bf16 layout (operand-role-agnostic):
//   u32 index for (row r, k-pair p): (r>>4)*1024 + (p>>2)*64 + (r&15)*4 + (p&3)
// MFMA A-frag read for (rowblock ag, kgroup ks): contiguous 1KB at
//   byte = ag*4096 + ks*1024 + lane*16   (lane holds row=lane&15, kslot=lane>>4)

// 4 rows per block (4 waves): l2-normalize input rows, emit f32 + frag bf16,
// count labels, and pos[row] = S * dot(fn, l2norm(weight[label])) in f32.
__global__ void prep_fn(const float* __restrict__ inp, const int* __restrict__ label,
                        const float* __restrict__ wt,
                        float* __restrict__ fn_f32, unsigned short* __restrict__ fn_fr,
                        float* __restrict__ counts, float* __restrict__ pos) {
    int row = blockIdx.x * 4 + (threadIdx.x >> 6);
    int lane = threadIdx.x & 63;
    float2 v = *(const float2*)(inp + row * D + lane * 2);
    float s = v.x * v.x + v.y * v.y;
    #pragma unroll
    for (int m = 1; m < 64; m <<= 1) s += __shfl_xor(s, m);
    float inv = 1.0f / fmaxf(sqrtf(s), 1e-12f);
    float a = v.x * inv, b = v.y * inv;
    *(float2*)(fn_f32 + row * D + lane * 2) = make_float2(a, b);
    unsigned pack = (unsigned)f2bf(a) | ((unsigned)f2bf(b) << 16);
    ((unsigned*)fn_fr)[(row >> 4) * 1024 + (lane >> 2) * 64 + ((row & 15) << 2) + (lane & 3)] = pack;

    int c = label[row];
    float2 wv = *(const float2*)(wt + c * D + lane * 2);
    float sw_ = wv.x * wv.x + wv.y * wv.y;
    float dt  = wv.x * a + wv.y * b;
    #pragma unroll
    for (int m = 1; m < 64; m <<= 1) { sw_ += __shfl_xor(sw_, m); dt += __shfl_xor(dt, m); }
    if (lane == 0) {
        float invw = 1.0f / fmaxf(sqrtf(sw_), 1e-12f);
        pos[row] = S_SCALE * dt * invw;
        atomicAdd(counts + c, 1.0f);
    }
}

// v7 main: prep_wn FUSED into the GEMM. Each block owns tile phases
// {x, x+256, ...} of the 1564 64-class tiles; per tile it loads the RAW f32
// weight rows (coalesced, 8 f32/thread), l2-normalizes in-kernel (16-lane
// shuffle reduce), writes the outw copy-or-zero (half 0 only), packs bf16 and
// ds_writes straight into the MFMA fragment layout, then MFMAs against the
// fn fragments held in registers. T14 schedule: tile t+1's global loads issue
// BEFORE tile t's MFMA+exp, normalize+commit after, ONE barrier per tile.
// No wn_fr intermediate (saves ~77 MB of HBM traffic + a whole kernel).
// Load for tile t+1:  v0..v3 = wt[rg][2*g16 + {0,1} + 32*s], 0 if padded.
#define LOADV()  do {                                                         \
    if (rg < NC) {                                                            \
        const float* p_ = wt + (size_t)rg * 128 + 2 * g16;                    \
        v0 = *(const float2*)(p_);      v1 = *(const float2*)(p_ + 32);       \
        v2 = *(const float2*)(p_ + 64); v3 = *(const float2*)(p_ + 96);       \
    } else { v0 = v1 = v2 = v3 = make_float2(0.f, 0.f); }                     \
} while (0)

// Normalize + outw + frag-layout ds_write into buf (thread owns row rloc,
// k-pairs p = g16 + 16*s -> u32 idx base + 256*s; ~4-way write conflict only).
#define COMMIT(buf) do {                                                      \
    float ss = v0.x*v0.x + v0.y*v0.y + v1.x*v1.x + v1.y*v1.y                  \
             + v2.x*v2.x + v2.y*v2.y + v3.x*v3.x + v3.y*v3.y;                 \
    ss += __shfl_xor(ss, 1); ss += __shfl_xor(ss, 2);                         \
    ss += __shfl_xor(ss, 4); ss += __shfl_xor(ss, 8);                         \
    float inv = 1.0f / fmaxf(sqrtf(ss), 1e-12f);                              \
    unsigned* Wu_ = (unsigned*)(buf);                                         \
    int base_ = (rloc >> 4) * 1024 + (g16 >> 2) * 64 + (rloc & 15) * 4 + (g16 & 3); \
    Wu_[base_]       = (unsigned)f2bf(v0.x*inv) | ((unsigned)f2bf(v0.y*inv) << 16); \
    Wu_[base_ + 256] = (unsigned)f2bf(v1.x*inv) | ((unsigned)f2bf(v1.y*inv) << 16); \
    Wu_[base_ + 512] = (unsigned)f2bf(v2.x*inv) | ((unsigned)f2bf(v2.y*inv) << 16); \
    Wu_[base_ + 768] = (unsigned)f2bf(v3.x*inv) | ((unsigned)f2bf(v3.y*inv) << 16); \
    if (writeout && rg < NC) {                                                \
        float cnt_ = counts[rg];                                              \
        float* op_ = outw + (size_t)rg * 128 + 2 * g16;                       \
        float2 z_ = make_float2(0.f, 0.f);                                    \
        *(float2*)(op_)      = (cnt_ > 0.f) ? z_ : v0;                        \
        *(float2*)(op_ + 32) = (cnt_ > 0.f) ? z_ : v1;                        \
        *(float2*)(op_ + 64) = (cnt_ > 0.f) ? z_ : v2;                        \
        *(float2*)(op_ + 96) = (cnt_ > 0.f) ? z_ : v3;                        \
    }                                                                         \
} while (0)

__global__ __launch_bounds__(1024, 4) void main_gemm(
    const unsigned short* __restrict__ fnfr, const float* __restrict__ wt,
    const float* __restrict__ counts, float* __restrict__ sumexp,
    float* __restrict__ outw) {
    __shared__ __align__(16) short Ws[2][8192];   // 2 x 16 KB frag tiles
    const int tid = threadIdx.x;
    const int lane = tid & 63, w = tid >> 6;      // 16 waves
    const int g16 = tid & 15;
    const int rloc = tid >> 4;                    // 0..63: tile-local class row
    const int half = blockIdx.y;                  // batch half (512 rows)
    const bool writeout = (half == 0);

    // fn B-fragments in regs (32 VGPRs), loaded once, pinned.
    bf16x8 bf[2][4];  // [cg][ks]
    {
        const char* gB = (const char*)fnfr + (size_t)(half * 32 + w * 2) * 4096 + lane * 16;
        #pragma unroll
        for (int cg = 0; cg < 2; cg++)
            #pragma unroll
            for (int ks = 0; ks < 4; ks++)
                bf[cg][ks] = *(const bf16x8*)(gB + cg * 4096 + ks * 1024);
    }
    #pragma unroll
    for (int cg = 0; cg < 2; cg++)
        #pragma unroll
        for (int ks = 0; ks < 4; ks++)
            asm volatile("" : "+v"(bf[cg][ks]));

    float sums[2] = {0.0f, 0.0f};
    float2 v0, v1, v2, v3;

    // prologue: tile t0 -> load, normalize, commit to buf 0
    int rg = blockIdx.x * 64 + rloc;
    LOADV();
    COMMIT(Ws[0]);
    __syncthreads();

    int cur = 0;
    for (int t = blockIdx.x; t < NT64; t += PHASES) {
        int nxt = t + PHASES;
        if (nxt < NT64) { rg = nxt * 64 + rloc; LOADV(); }   // issue early (T14)

        f32x4 acc[4][2];
        #pragma unroll
        for (int ag = 0; ag < 4; ag++)
            #pragma unroll
            for (int cg = 0; cg < 2; cg++)
                acc[ag][cg] = (f32x4){0.0f, 0.0f, 0.0f, 0.0f};

        const char* W = (const char*)Ws[cur];
        #pragma unroll
        for (int ks = 0; ks < 4; ks++) {
            bf16x8 a0 = *(const bf16x8*)(W +     0 + ks * 1024 + lane * 16);
            bf16x8 a1 = *(const bf16x8*)(W +  4096 + ks * 1024 + lane * 16);
            bf16x8 a2 = *(const bf16x8*)(W +  8192 + ks * 1024 + lane * 16);
            bf16x8 a3 = *(const bf16x8*)(W + 12288 + ks * 1024 + lane * 16);
            acc[0][0] = __builtin_amdgcn_mfma_f32_16x16x32_bf16(a0, bf[0][ks], acc[0][0], 0, 0, 0);
            acc[0][1] = __builtin_amdgcn_mfma_f32_16x16x32_bf16(a0, bf[1][ks], acc[0][1], 0, 0, 0);
            acc[1][0] = __builtin_amdgcn_mfma_f32_16x16x32_bf16(a1, bf[0][ks], acc[1][0], 0, 0, 0);
            acc[1][1] = __builtin_amdgcn_mfma_f32_16x16x32_bf16(a1, bf[1][ks], acc[1][1], 0, 0, 0);
            acc[2][0] = __builtin_amdgcn_mfma_f32_16x16x32_bf16(a2, bf[0][ks], acc[2][0], 0, 0, 0);
            acc[2][1] = __builtin_amdgcn_mfma_f32_16x16x32_bf16(a2, bf[1][ks], acc[2][1], 0, 0, 0);
            acc[3][0] = __builtin_amdgcn_mfma_f32_16x16x32_bf16(a3, bf[0][ks], acc[3][0], 0, 0, 0);
            acc[3][1] = __builtin_amdgcn_mfma_f32_16x16x32_bf16(a3, bf[1][ks], acc[3][1], 0, 0, 0);
        }

        // exp(30v-30) = exp2(fma(v, 30log2e, -30log2e)); class axis is (ag, r,
        // quad) -> pure per-lane sums, no cross-lane work per tile.
        #pragma unroll
        for (int ag = 0; ag < 4; ag++)
            #pragma unroll
            for (int r = 0; r < 4; r++) {
                sums[0] += __builtin_amdgcn_exp2f(fmaf(acc[ag][0][r], S2LOG2E, -S2LOG2E));
                sums[1] += __builtin_amdgcn_exp2f(fmaf(acc[ag][1][r], S2LOG2E, -S2LOG2E));
            }

        if (nxt < NT64) COMMIT(Ws[cur ^ 1]);   // loads have had MFMA+exp to land
        __syncthreads();                       // ds_writes visible for next iter
        cur ^= 1;
    }

    // fold the quad axis (class rows live in quads) and flush once per wave.
    #pragma unroll
    for (int cg = 0; cg < 2; cg++) {
        float s = sums[cg];
        s += __shfl_xor(s, 16);
        s += __shfl_xor(s, 32);
        if (lane < 16)
            atomicAdd(sumexp + half * 512 + w * 32 + cg * 16 + lane, s);
    }
}

// tail: blocks 0..511 = addmean (2 rows each); block 512 = loss.
__global__ void tail_k(const float* __restrict__ fn_f32, const int* __restrict__ label,
                       const float* __restrict__ counts, float* __restrict__ outw,
                       const float* __restrict__ sumexp, const float* __restrict__ pos,
                       float* __restrict__ out) {
    if (blockIdx.x < 512) {
        int b = blockIdx.x * 2 + (threadIdx.x >> 7);
        int t = threadIdx.x & 127;
        int c = label[b];
        atomicAdd(outw + (size_t)c * D + t, fn_f32[b * D + t] / counts[c]);
        return;
    }
    // loss = mean softplus(M + 30 + log(sum_all - exp(pos-30)) - pos)
    __shared__ float red[256];
    int t = threadIdx.x;
    float acc = 0.0f;
    #pragma unroll
    for (int i = 0; i < 4; i++) {
        int r = t + i * 256;
        float p = pos[r];
        float sneg = fmaxf(sumexp[r] - __expf(p - 30.0f), 1e-38f);
        float lse = 30.0f + logf(sneg);
        float z = MARGIN + lse - p;
        acc += fmaxf(z, 0.0f) + log1pf(__expf(-fabsf(z)));
    }
    red[t] = acc;
    __syncthreads();
    for (int s = 128; s > 0; s >>= 1) {
        if (t < s) red[t] += red[t + s];
        __syncthreads();
    }
    if (t == 0) out[0] = red[0] * (1.0f / 1024.0f);
}

extern "C" void kernel_launch(void* const* d_in, const int* in_sizes, int n_in,
                              void* d_out, int out_size, void* d_ws, size_t ws_size,
                              hipStream_t stream) {
    (void)in_sizes; (void)n_in; (void)out_size; (void)ws_size;
    const float* inp   = (const float*)d_in[0];
    const int*   label = (const int*)d_in[1];
    const float* wt    = (const float*)d_in[2];
    float* out = (float*)d_out;

    char* w = (char*)d_ws;
    float*          fn_f32 = (float*)(w);                     // 524288 B
    unsigned short* fn_fr  = (unsigned short*)(w + 524288);   // 262144 B
    float*          sumexp = (float*)(w + 26411008);          // 4096 B
    float*          counts = (float*)(w + 26415104);          // 400000 B
    float*          pos    = (float*)(w + 26815104);          // 4096 B

    // zero sumexp + counts (contiguous)
    hipMemsetAsync(w + 26411008, 0, 404096, stream);

    prep_fn<<<BS / 4, 256, 0, stream>>>(inp, label, wt, fn_f32, fn_fr, counts, pos);
    main_gemm<<<dim3(PHASES, 2), 1024, 0, stream>>>(fn_fr, wt, counts, sumexp, out + 1);
    tail_k<<<513, 256, 0, stream>>>(fn_f32, label, counts, out + 1, sumexp, pos, out);
}